// Round 12
// baseline (4233.097 us; speedup 1.0000x reference)
//
#include <hip/hip_runtime.h>
#include <stdint.h>

#define NB 16
#define HH 128
#define WW 128
#define L (HH*WW)        // 16384
#define CIN 3
#define HID 256
#define NC 21
#define CHUNK 256
#define NCHUNKS (L/CHUNK)   // 64
#define T_PER 32            // t's per wave in k_bp
#define NPACK (L/4)         // 4096 packs of 4 timesteps

// ---------------- K1: conv -> fp32 emissions, TRANSPOSED em_T[b][c][t], LDS input tile ----------------
__global__ __launch_bounds__(256) void k_conv(
    const float* __restrict__ x, const float* __restrict__ w1,
    const float* __restrict__ b1, const float* __restrict__ w2,
    const float* __restrict__ b2, float* __restrict__ emT)
{
    __shared__ float xs[CIN*4*WW];        // 3 ic x 4 rows x 128 cols = 6144 B
    int tid = threadIdx.x;
    int g  = blockIdx.x * 256 + tid;      // 0..B*L-1
    int b  = g >> 14;
    int t0 = (blockIdx.x * 256) & (L-1);  // first t of block (multiple of 256)
    int y0 = t0 >> 7;                     // first of the block's 2 rows
    int dy = tid >> 7;                    // 0 or 1
    int xx = tid & (WW-1);
    int t  = t0 + tid;

    const float* xb = x + (size_t)b * CIN * L;
    for (int i = tid; i < CIN*4*WW; i += 256) {
        int ic  = i >> 9;                 // /512
        int rem = i & 511;
        int rr  = rem >> 7;               // 0..3
        int cc  = rem & 127;
        int row = y0 - 1 + rr;
        xs[i] = (row >= 0 && row < HH) ? xb[ic*L + (row<<7) + cc] : 0.f;
    }
    __syncthreads();

    double p[27];
    #pragma unroll
    for (int ic = 0; ic < CIN; ++ic) {
        #pragma unroll
        for (int ky = 0; ky < 3; ++ky) {
            #pragma unroll
            for (int kx = 0; kx < 3; ++kx) {
                int xc = xx + kx - 1;
                float v = (xc >= 0 && xc < WW) ? xs[ic*512 + (dy+ky)*128 + xc] : 0.f;
                p[ic*9 + ky*3 + kx] = (double)v;
            }
        }
    }

    double acc[NC];
    #pragma unroll
    for (int c = 0; c < NC; ++c) acc[c] = 0.0;

    #pragma unroll 2
    for (int oc = 0; oc < HID; ++oc) {
        double hv = 0.0;                              // conv1 accum
        #pragma unroll
        for (int j = 0; j < 27; ++j) hv += (double)w1[oc*27 + j] * p[j];
        float h32 = (float)hv;                        // round conv1 to fp32
        h32 = h32 + b1[oc];                           // fp32 elementwise bias
        h32 = fmaxf(h32, 0.f);                        // relu (fp32)
        double hd = (double)h32;
        #pragma unroll
        for (int c = 0; c < NC; ++c) acc[c] += (double)w2[c*HID + oc] * hd;
    }
    float* dstb = emT + (size_t)b * NC * L;
    #pragma unroll
    for (int c = 0; c < NC; ++c) {
        float e32 = (float)acc[c];                    // round conv2 to fp32
        dstb[(size_t)c * L + t] = e32 + b2[c];        // transposed store (coalesced in t)
    }
}

// ---------------- K2a: 4 chains/wave — lane-split x interleave, full-window plain-write ----------
// s'[n] = fl( max_p fl(s[p]+T[p][n]) + e[n] ) — bitwise equal to ref (same candidate set, RNE
// monotonicity; max computed fully in-register per lane, single writer per slot).
// Ledger (cy/step, 1 chain/wave family): R7=229 FLOOR (R11=236 confirmed the last RMW cut is a
// wash). 229 ~ 50% bare LDS RT latency -> hide it with independent chains in ONE wave's stream:
//  (a) lane-split: lanes 0-20 = chain X, 32-52 = chain Y share every instruction (per-lane LDS
//      base) -> 2 chains/slot for free;
//  (b) interleave 2 slots: {S0-rd, S1-rd, S0-cmp+wr, S1-cmp+wr} — S1's reads are in flight
//      while S0 waits, S1's compute fills S0's RT shadow. 4 chains/wave, 4 blocks total.
// Per chain-step: 6 broadcast ds_read_b128 (2 addrs/instr = free 2-way) + 21 add + 10 max3 +
// 1 add + 1 plain ds_write_b32 (single writer per slot — NO atomics, NO RMW, NO readback; sc
// quads straight from regs, R8-proven path). Pads [21,24) loaded but never used (dead lanes of
// R5 read) -> no init needed, no -inf anywhere.
// Ordering: all-plain DS, runtime offsets -> may-alias -> program order preserved; ping-pong
// write->read ordered by in-order DS pipe (R5/R7-proven). Est 65-110 cy/step.
__global__ __launch_bounds__(64) void k_scores(
    const float* __restrict__ emT, const float* __restrict__ start,
    const float* __restrict__ endt, const float* __restrict__ trans,
    float* __restrict__ sc, int* __restrict__ last_tag)
{
    __shared__ float smem[256];            // 4 chains x {buf0,buf1} x 24 floats = [0,192); dump [192,256)
    __shared__ float fin[4*NC];
    int l   = threadIdx.x;
    int u   = l & 31;
    int hi  = l >> 5;                      // lower/upper half = which chain of the slot
    int n   = u < NC ? u : NC-1;           // my state (lanes u>=21 shadow n=20, outputs unused)
    int blk = blockIdx.x;                  // 4 blocks; block handles chains 4*blk .. 4*blk+3

    int b0 = 4*blk + hi;                   // slot0 chain
    int b1 = 4*blk + 2 + hi;               // slot1 chain
    int cb0 = hi * 48;                     // slot0 LDS base (floats): chains 0/1 -> 0/48
    int cb1 = (2 + hi) * 48;               // slot1: chains 2/3 -> 96/144

    bool st = (u < NC);
    int ws0p0 = st ? (cb0 + u)      : (192 + l);   // write slots (dump for shadow lanes)
    int ws0p1 = st ? (cb0 + 24 + u) : (192 + l);
    int ws1p0 = st ? (cb1 + u)      : (192 + l);
    int ws1p1 = st ? (cb1 + 24 + u) : (192 + l);

    const float4* er0 = (const float4*)(emT + ((size_t)b0 * NC + n) * L);
    const float4* er1 = (const float4*)(emT + ((size_t)b1 * NC + n) * L);
    float* scp0 = sc + (size_t)b0 * NC * L;
    float* scp1 = sc + (size_t)b1 * NC * L;

    float tc[NC];                          // T[p][n] — shared by both my chains (same n)
    #pragma unroll
    for (int p = 0; p < NC; ++p) tc[p] = trans[p*NC + n];
    #pragma unroll
    for (int p = 0; p < NC; ++p) asm volatile("" : "+v"(tc[p]));

    // COL: full-window max for one chain from 6 float4 regs; write + register output.
    #define COL(R0,R1,R2,R3,R4,R5, EV, WSL, OUT) { \
        float w0  = R0.x + tc[0],  w1  = R0.y + tc[1],  w2  = R0.z + tc[2],  w3  = R0.w + tc[3]; \
        float w4  = R1.x + tc[4],  w5  = R1.y + tc[5],  w6  = R1.z + tc[6],  w7  = R1.w + tc[7]; \
        float w8  = R2.x + tc[8],  w9  = R2.y + tc[9],  w10 = R2.z + tc[10], w11 = R2.w + tc[11]; \
        float w12 = R3.x + tc[12], w13 = R3.y + tc[13], w14 = R3.z + tc[14], w15 = R3.w + tc[15]; \
        float w16 = R4.x + tc[16], w17 = R4.y + tc[17], w18 = R4.z + tc[18], w19 = R4.w + tc[19]; \
        float w20 = R5.x + tc[20];                       /* R5.yzw = pads, never used */ \
        float m0 = fmaxf(fmaxf(w0,  w1),  w2); \
        float m1 = fmaxf(fmaxf(w3,  w4),  w5); \
        float m2 = fmaxf(fmaxf(w6,  w7),  w8); \
        float m3 = fmaxf(fmaxf(w9,  w10), w11); \
        float m4 = fmaxf(fmaxf(w12, w13), w14); \
        float m5 = fmaxf(fmaxf(w15, w16), w17); \
        float m6 = fmaxf(fmaxf(w18, w19), w20); \
        float z0 = fmaxf(fmaxf(m0, m1), m2); \
        float z1 = fmaxf(fmaxf(m3, m4), m5); \
        float qv = fmaxf(fmaxf(z0, z1), m6) + (EV);      /* q = fl(pr + e[n]) */ \
        smem[WSL] = qv; \
        OUT = qv; }

    // STEPPAIR: one timestep for BOTH slots. Reads first (both slots — S1's fill S0's shadow),
    // then compute+write S0, compute+write S1.
    #define STEPPAIR(PPR, PPW, EV0, EV1, O0, O1) { \
        const float* pa_ = &smem[cb0 + (PPR)*24]; \
        const float* pb_ = &smem[cb1 + (PPR)*24]; \
        float4 A0 = *(const float4*)(pa_+0),  A1 = *(const float4*)(pa_+4),  A2 = *(const float4*)(pa_+8); \
        float4 A3 = *(const float4*)(pa_+12), A4 = *(const float4*)(pa_+16), A5 = *(const float4*)(pa_+20); \
        float4 B0 = *(const float4*)(pb_+0),  B1 = *(const float4*)(pb_+4),  B2 = *(const float4*)(pb_+8); \
        float4 B3 = *(const float4*)(pb_+12), B4 = *(const float4*)(pb_+16), B5 = *(const float4*)(pb_+20); \
        COL(A0,A1,A2,A3,A4,A5, EV0, (PPW) ? ws0p1 : ws0p0, O0) \
        COL(B0,B1,B2,B3,B4,B5, EV1, (PPW) ? ws1p1 : ws1p0, O1) \
    }

    float4 e0a = er0[0], e0b = er0[1];
    float4 e1a = er1[0], e1b = er1[1];

    float q00, q01, q02, q03, q10, q11, q12, q13;

    // ---- t=0 init + pack 0 (t=1..3) ----
    q00 = e0a.x + start[n];                // s0 = fl(em[0]+start), ref order
    q10 = e1a.x + start[n];
    smem[ws0p0] = q00;                     // buf0 of each chain
    smem[ws1p0] = q10;
    {
        float4 e0 = e0a, e1 = e1a;
        e0a = er0[2]; e1a = er1[2];
        STEPPAIR(0, 1, e0.y, e1.y, q01, q11)   // t=1: reads buf0, writes buf1
        STEPPAIR(1, 0, e0.z, e1.z, q02, q12)   // t=2
        STEPPAIR(0, 1, e0.w, e1.w, q03, q13)   // t=3
        if (st) {
            *(float4*)(scp0 + n*4) = make_float4(q00, q01, q02, q03);
            *(float4*)(scp1 + n*4) = make_float4(q10, q11, q12, q13);
        }
    }

    // ---- packs 1..4095: 4 steps, then sc quads straight from registers ----
    for (int k = 1; k < NPACK; ++k) {
        float4 e0 = (k & 1) ? e0b : e0a;
        float4 e1 = (k & 1) ? e1b : e1a;
        int kp = k + 2; if (kp > NPACK-1) kp = NPACK-1;
        if (k & 1) { e0b = er0[kp]; e1b = er1[kp]; }
        else       { e0a = er0[kp]; e1a = er1[kp]; }

        STEPPAIR(1, 0, e0.x, e1.x, q00, q10)   // t=4k
        STEPPAIR(0, 1, e0.y, e1.y, q01, q11)   // t=4k+1
        STEPPAIR(1, 0, e0.z, e1.z, q02, q12)   // t=4k+2
        STEPPAIR(0, 1, e0.w, e1.w, q03, q13)   // t=4k+3
        if (st) {
            *(float4*)(scp0 + k*84 + n*4) = make_float4(q00, q01, q02, q03);
            *(float4*)(scp1 + k*84 + n*4) = make_float4(q10, q11, q12, q13);
        }
    }
    #undef STEPPAIR
    #undef COL

    if (st) {
        fin[hi*NC + n]     = q03;          // slot0 chain (block-chain index hi)
        fin[(2+hi)*NC + n] = q13;          // slot1 chain (block-chain index 2+hi)
    }
    __syncthreads();
    if (l < 4) {
        int c = l;
        float bv = fin[c*NC + 0] + endt[0]; int bt = 0;
        #pragma unroll
        for (int j = 1; j < NC; ++j) {
            float v = fin[c*NC + j] + endt[j];
            if (v > bv) { bv = v; bt = j; }
        }
        last_tag[4*blk + c] = bt;
    }
}

// ---------------- K2b: parallel backpointer recovery ----------------
// bp[t][n] = first p with fl(fl(s_{t-1}[p]+T[p][n])+e[t][n]) == s_t[n]
__global__ __launch_bounds__(256) void k_bp(
    const float* __restrict__ emT, const float* __restrict__ sc,
    const float* __restrict__ trans, uint8_t* __restrict__ bp)
{
    int wave = threadIdx.x >> 6;
    int lane = threadIdx.x & 63;
    int ne   = lane < NC ? lane : NC-1;

    int bidx  = blockIdx.x;
    int b     = bidx >> 7;                              // 128 blocks per batch
    int tbase = (bidx & 127) * (4*T_PER) + wave*T_PER;

    const float* emb = emT + (size_t)b * NC * L;
    const float* scp = sc  + (size_t)b * NC * L;
    uint8_t*     bpb = bp  + (size_t)b * L * NC;

    float tc[NC];
    #pragma unroll
    for (int pp = 0; pp < NC; ++pp) tc[pp] = trans[pp*NC + ne];

    for (int t = tbase; t < tbase + T_PER; ++t) {
        if (t == 0) continue;
        float target = scp[(t>>2)*84 + ne*4 + (t&3)];
        float e      = emb[(size_t)ne * L + t];
        const float* sp = scp + ((t-1)>>2)*84 + ((t-1)&3);
        int fi = 0;
        #pragma unroll
        for (int pp = NC-1; pp >= 0; --pp) {
            float cand = (sp[pp*4] + tc[pp]) + e;
            if (cand == target) fi = pp;
        }
        if (lane < NC) bpb[(size_t)t * NC + ne] = (uint8_t)fi;
    }
}

// ---------------- K3a: per-chunk jump tables, SEGMENTED chase (exact) ----------------
__global__ __launch_bounds__(64) void k_jump(
    const uint8_t* __restrict__ bp, uint8_t* __restrict__ J)
{
    __shared__ uint32_t lds4[CHUNK*NC/4];    // 5376 B of bp rows [cs..ce)
    __shared__ uint8_t  segJ[8*NC];          // 168 B
    int l   = threadIdx.x;
    int bid = blockIdx.x;
    int b   = bid / (NCHUNKS-1);
    int k   = bid % (NCHUNKS-1) + 1;         // chunks 1..63
    int cs  = k * CHUNK;

    const uint32_t* src = (const uint32_t*)(bp + (size_t)b * L * NC + (size_t)cs * NC);
    for (int i = l; i < CHUNK*NC/4; i += 64) lds4[i] = src[i];
    __syncthreads();
    const uint8_t* lb = (const uint8_t*)lds4;

    // 168 = 8 segs x 21 hyps; chase c -> (s=c/21, h=c%21), rows s*32+31 .. s*32
    int c0 = l, c1 = l + 63, c2 = l + 126;
    bool v2 = (c2 < 8*NC);
    int t0 = c0 % NC, t1 = c1 % NC, t2 = v2 ? (c2 % NC) : 0;
    int r0 = (c0 / NC) * 32, r1 = (c1 / NC) * 32, r2 = v2 ? (c2 / NC) * 32 : 0;
    for (int i = 31; i >= 0; --i) {          // 3 independent chains -> pipelined
        t0 = lb[(r0+i)*NC + t0];
        t1 = lb[(r1+i)*NC + t1];
        if (v2) t2 = lb[(r2+i)*NC + t2];
    }
    segJ[c0] = (uint8_t)t0;
    segJ[c1] = (uint8_t)t1;
    if (v2) segJ[c2] = (uint8_t)t2;
    __syncthreads();

    if (l < NC) {
        int tag = l;
        #pragma unroll
        for (int s = 7; s >= 0; --s) tag = segJ[s*NC + tag];
        J[((size_t)b * NCHUNKS + k) * NC + l] = (uint8_t)tag;
    }
}

// ---------------- K3b: thread chunk entries through jump tables (LDS-staged J) ----------------
__global__ __launch_bounds__(64) void k_seq(
    const uint8_t* __restrict__ J, const int* __restrict__ last_tag,
    uint8_t* __restrict__ ent)
{
    __shared__ uint32_t ldsJ4[NB*NCHUNKS*NC/4];   // 21504 B
    int l = threadIdx.x;
    const uint32_t* src = (const uint32_t*)J;
    for (int i = l; i < NB*NCHUNKS*NC/4; i += 64) ldsJ4[i] = src[i];
    __syncthreads();
    const uint8_t* lj = (const uint8_t*)ldsJ4;

    if (l < NB) {
        int b = l;
        int tag = last_tag[b];                       // tag at t = L-1
        ent[b * NCHUNKS + 63] = (uint8_t)tag;
        for (int k = NCHUNKS-1; k >= 1; --k) {
            tag = lj[((size_t)b * NCHUNKS + k) * NC + tag];
            ent[b * NCHUNKS + (k-1)] = (uint8_t)tag;
        }
    }
}

// ---------------- K3c: per-chunk output, SEGMENTED re-walk from exact seed ----------------
__global__ __launch_bounds__(64) void k_out(
    const uint8_t* __restrict__ bp, const uint8_t* __restrict__ ent,
    int* __restrict__ out)
{
    __shared__ uint32_t lds4[CHUNK*NC/4];
    __shared__ uint8_t  segJ[8*NC];
    __shared__ uint8_t  E[8];
    __shared__ int      tags[CHUNK];
    int l   = threadIdx.x;
    int bid = blockIdx.x;
    int b   = bid >> 6;
    int k   = bid & (NCHUNKS-1);
    int cs  = k * CHUNK;

    const uint32_t* src = (const uint32_t*)(bp + (size_t)b * L * NC + (size_t)cs * NC);
    for (int i = l; i < CHUNK*NC/4; i += 64) lds4[i] = src[i];
    __syncthreads();
    const uint8_t* lb = (const uint8_t*)lds4;

    // phase 2: segment tables (chunk 0 seg 0 crosses t=0: its result is never used)
    int c0 = l, c1 = l + 63, c2 = l + 126;
    bool v2 = (c2 < 8*NC);
    int t0 = c0 % NC, t1 = c1 % NC, t2 = v2 ? (c2 % NC) : 0;
    int r0 = (c0 / NC) * 32, r1 = (c1 / NC) * 32, r2 = v2 ? (c2 / NC) * 32 : 0;
    for (int i = 31; i >= 0; --i) {
        t0 = lb[(r0+i)*NC + t0];
        t1 = lb[(r1+i)*NC + t1];
        if (v2) t2 = lb[(r2+i)*NC + t2];
    }
    segJ[c0] = (uint8_t)(t0 & 31);           // mask: chunk-0/seg-0 garbage stays in-bounds
    segJ[c1] = (uint8_t)(t1 & 31);
    if (v2) segJ[c2] = (uint8_t)(t2 & 31);
    __syncthreads();

    // phase 3: compose segment entry tags E[s] = tag at position cs + 32s + 31
    if (l == 0) {
        int tag = ent[b * NCHUNKS + k];              // exact tag at ce-1
        E[7] = (uint8_t)tag;
        #pragma unroll
        for (int s = 7; s >= 1; --s) { tag = segJ[s*NC + tag]; E[s-1] = (uint8_t)tag; }
    }
    __syncthreads();

    // phase 4: 8 lanes re-walk their 32 rows
    if (l < 8) {
        int tag = E[l];
        int rb  = l * 32;
        for (int i = 31; i >= 0; --i) {              // t = cs+rb+i down to cs+rb
            tags[rb + i] = tag;
            tag = lb[(rb+i)*NC + tag];               // hop at t=0 (chunk 0) unused
        }
    }
    __syncthreads();

    int4* ob = (int4*)(out + (size_t)b * L + cs);
    ob[l] = ((const int4*)tags)[l];                  // 64 lanes x int4 = 256 ints
}

extern "C" void kernel_launch(void* const* d_in, const int* in_sizes, int n_in,
                              void* d_out, int out_size, void* d_ws, size_t ws_size,
                              hipStream_t stream) {
    const float* x  = (const float*)d_in[0];
    const float* w1 = (const float*)d_in[1];
    const float* b1 = (const float*)d_in[2];
    const float* w2 = (const float*)d_in[3];
    const float* b2 = (const float*)d_in[4];
    const float* st = (const float*)d_in[5];
    const float* en = (const float*)d_in[6];
    const float* tr = (const float*)d_in[7];
    int* out = (int*)d_out;

    char* ws = (char*)d_ws;
    float*   em = (float*)ws;                                    // em_T: 22,020,096 B
    float*   sc = (float*)(ws + (size_t)NB*L*NC*4);              // packed scores: 22,020,096 B
    uint8_t* bp = (uint8_t*)(ws + (size_t)NB*L*NC*8);            // 5,505,024 B
    int*     lt = (int*)(ws + (size_t)NB*L*NC*9);                // int[NB]
    // J/ent alias the em region: em is dead after k_bp completes (stream-ordered).
    uint8_t* J   = (uint8_t*)ws;                                 // NB*64*21 = 21,504 B
    uint8_t* ent = (uint8_t*)ws + 21504;                         // NB*64 = 1,024 B

    k_conv  <<<dim3(NB*L/256),       dim3(256), 0, stream>>>(x, w1, b1, w2, b2, em);
    k_scores<<<dim3(NB/4),           dim3(64),  0, stream>>>(em, st, en, tr, sc, lt);
    k_bp    <<<dim3(NB*128),         dim3(256), 0, stream>>>(em, sc, tr, bp);
    k_jump  <<<dim3(NB*(NCHUNKS-1)), dim3(64),  0, stream>>>(bp, J);
    k_seq   <<<dim3(1),              dim3(64),  0, stream>>>(J, lt, ent);
    k_out   <<<dim3(NB*NCHUNKS),     dim3(64),  0, stream>>>(bp, ent, out);
}

// Round 13
// 1941.914 us; speedup vs baseline: 2.1799x; 2.1799x over previous
//
#include <hip/hip_runtime.h>
#include <stdint.h>

#define NB 16
#define HH 128
#define WW 128
#define L (HH*WW)        // 16384
#define CIN 3
#define HID 256
#define NC 21
#define CHUNK 256
#define NCHUNKS (L/CHUNK)   // 64
#define T_PER 32            // t's per wave in k_bp
#define NPACK (L/4)         // 4096 packs of 4 timesteps

// ---------------- K1: conv -> fp32 emissions, TRANSPOSED em_T[b][c][t], LDS input tile ----------------
__global__ __launch_bounds__(256) void k_conv(
    const float* __restrict__ x, const float* __restrict__ w1,
    const float* __restrict__ b1, const float* __restrict__ w2,
    const float* __restrict__ b2, float* __restrict__ emT)
{
    __shared__ float xs[CIN*4*WW];        // 3 ic x 4 rows x 128 cols = 6144 B
    int tid = threadIdx.x;
    int g  = blockIdx.x * 256 + tid;      // 0..B*L-1
    int b  = g >> 14;
    int t0 = (blockIdx.x * 256) & (L-1);  // first t of block (multiple of 256)
    int y0 = t0 >> 7;                     // first of the block's 2 rows
    int dy = tid >> 7;                    // 0 or 1
    int xx = tid & (WW-1);
    int t  = t0 + tid;

    const float* xb = x + (size_t)b * CIN * L;
    for (int i = tid; i < CIN*4*WW; i += 256) {
        int ic  = i >> 9;                 // /512
        int rem = i & 511;
        int rr  = rem >> 7;               // 0..3
        int cc  = rem & 127;
        int row = y0 - 1 + rr;
        xs[i] = (row >= 0 && row < HH) ? xb[ic*L + (row<<7) + cc] : 0.f;
    }
    __syncthreads();

    double p[27];
    #pragma unroll
    for (int ic = 0; ic < CIN; ++ic) {
        #pragma unroll
        for (int ky = 0; ky < 3; ++ky) {
            #pragma unroll
            for (int kx = 0; kx < 3; ++kx) {
                int xc = xx + kx - 1;
                float v = (xc >= 0 && xc < WW) ? xs[ic*512 + (dy+ky)*128 + xc] : 0.f;
                p[ic*9 + ky*3 + kx] = (double)v;
            }
        }
    }

    double acc[NC];
    #pragma unroll
    for (int c = 0; c < NC; ++c) acc[c] = 0.0;

    #pragma unroll 2
    for (int oc = 0; oc < HID; ++oc) {
        double hv = 0.0;                              // conv1 accum
        #pragma unroll
        for (int j = 0; j < 27; ++j) hv += (double)w1[oc*27 + j] * p[j];
        float h32 = (float)hv;                        // round conv1 to fp32
        h32 = h32 + b1[oc];                           // fp32 elementwise bias
        h32 = fmaxf(h32, 0.f);                        // relu (fp32)
        double hd = (double)h32;
        #pragma unroll
        for (int c = 0; c < NC; ++c) acc[c] += (double)w2[c*HID + oc] * hd;
    }
    float* dstb = emT + (size_t)b * NC * L;
    #pragma unroll
    for (int c = 0; c < NC; ++c) {
        float e32 = (float)acc[c];                    // round conv2 to fp32
        dstb[(size_t)c * L + t] = e32 + b2[c];        // transposed store (coalesced in t)
    }
}

// ---------------- K2a: LDS ds_max recursion, 4 DS ops/step (R7 — MEASURED FLOOR, 229 cy/step) ----
// s'[n] = fl( max_p fl(s[p]+T[p][n]) + e[n] ) — bitwise equal to ref by RNE monotonicity:
// q_c = fl(max_{p in W_c} fl(s[p]+T) + e) = max_{W_c} fl(fl(s+T)+e); ds_max over 3 copies
// gives the exact 21-way value. Candidate set identical to ref -> sc bit-identical.
// FINAL ledger (cy/step, wall): R7=229 BEST · R11=236 · R5=237 · R10=265 · R8=283 · 314 · R6=325
// · R2=346 · R1=421 · R3=551 · R12=566(4-chain). Floor decomposition vs measured constants:
// ~120 LDS round-trip + ~45 DS-pipe (2 reads + wrxchg + 3-way ds_max) + ~60 VALU/issue ~ 225.
// Laws established: (1) only the LDS ALU combines cheaply — register-side combines (readlane/
// bpermute-2nd-level/permlane/DPP) cost >=40cy each on the dependent chain; (2) issue-stream
// insertions between reads and ds_max cost their issue cycles; (3) wave-multiplexing chains
// ADDS work to the serial stream (R12: wall/step 229->566) since batch parallelism is free;
// (4) the fl-rounding chain (bit-exact tags) forbids multi-step composition -> 16384 serial
// steps irreducible. 16384 x 229cy / 2.4GHz = 1.56ms = the k_scores latency floor.
#define NEGINF (-__builtin_huge_valf())

__global__ __launch_bounds__(64) void k_scores(
    const float* __restrict__ emT, const float* __restrict__ start,
    const float* __restrict__ endt, const float* __restrict__ trans,
    float* __restrict__ sc, int* __restrict__ last_tag)
{
    __shared__ float smem[128];            // two 64-float ping-pong buffers
    __shared__ float fin[NC];
    int l = threadIdx.x;
    int b = blockIdx.x;
    int c = l / 21; if (c > 2) c = 2;      // copy 0/1/2; lane 63 dups (2,20)
    int n = l - c*21; if (n > 20) n = 20;  // my state
    int wb = 8*c;                          // my p-window: floats [8c .. 8c+7]
    int mslot = (l == 63) ? 63 : n;        // lane63 maxes into dump slot 63 (3-way not 4-way)

    const float4* er4 = (const float4*)(emT + ((size_t)b * NC + n) * L);
    float*        scp = sc + (size_t)b * NC * L;          // 84 floats per pack

    // 8 transition constants T[wb+i][n]; -inf for p>20 (window pad)
    float tc0, tc1, tc2, tc3, tc4, tc5, tc6, tc7;
    {
        int p0=wb, p1=wb+1, p2=wb+2, p3=wb+3, p4=wb+4, p5=wb+5, p6=wb+6, p7=wb+7;
        tc0 = trans[p0*NC + n];
        tc1 = trans[p1*NC + n];
        tc2 = trans[p2*NC + n];
        tc3 = trans[p3*NC + n];
        tc4 = trans[p4*NC + n];
        tc5 = (p5 < NC) ? trans[p5*NC + n] : NEGINF;
        tc6 = (p6 < NC) ? trans[p6*NC + n] : NEGINF;
        tc7 = (p7 < NC) ? trans[p7*NC + n] : NEGINF;
    }
    asm volatile("" : "+v"(tc0), "+v"(tc1), "+v"(tc2), "+v"(tc3));
    asm volatile("" : "+v"(tc4), "+v"(tc5), "+v"(tc6), "+v"(tc7));

    // STEP(CUR,NXT): window reads of CUR (critical, first); wrxchg NXT[l] -> RB =
    // s_{t-2}[l] and NXT[l]=-inf (off-path); VALU; ds_max q into NXT[mslot].
    #define STEP(CUR, NXT, EV, RB) { \
        float4 ra  = *(const float4*)&smem[(CUR)*64 + wb]; \
        float4 rb4 = *(const float4*)&smem[(CUR)*64 + wb + 4]; \
        RB = __hip_atomic_exchange(&smem[(NXT)*64 + l], NEGINF, \
                 __ATOMIC_RELAXED, __HIP_MEMORY_SCOPE_WORKGROUP);   /* ds_wrxchg_rtn_b32 */ \
        float w0 = ra.x  + tc0, w1 = ra.y  + tc1, w2 = ra.z  + tc2, w3 = ra.w  + tc3; \
        float w4 = rb4.x + tc4, w5 = rb4.y + tc5, w6 = rb4.z + tc6, w7 = rb4.w + tc7; \
        float m0 = fmaxf(fmaxf(w0, w1), w2); \
        float m1 = fmaxf(fmaxf(w3, w4), w5); \
        float m2 = fmaxf(w6, w7); \
        float q  = fmaxf(fmaxf(m0, m1), m2) + (EV);        /* q_c = fl(pr_c + e[n]) */ \
        (void)__hip_atomic_fetch_max(&smem[(NXT)*64 + mslot], q, \
                 __ATOMIC_RELAXED, __HIP_MEMORY_SCOPE_WORKGROUP);   /* ds_max_f32 */ \
    }

    float4 ebuf0 = er4[0];
    float4 ebuf1 = er4[1];

    // ---- t=0 init + pack 0 (t=1..3) ----
    float v0 = ebuf0.x + start[n];         // s0 = fl(em[0]+start), ref order
    smem[l] = (l < NC) ? v0 : NEGINF;      // buf0 = s0, slots 21..63 = -inf (buf1 init'd by t=1's wrxchg)
    float h0 = v0, h1;                     // two oldest pending quad entries
    {
        float4 ev = ebuf0;
        ebuf0 = er4[2];
        float rb1, rb2, rb3;
        STEP(0, 1, ev.y, rb1)              // t=1: rb1 = garbage (buf1 uninit), discarded
        STEP(1, 0, ev.z, rb2)              // t=2: rb2 = s0 (dup of v0), discarded
        STEP(0, 1, ev.w, rb3)              // t=3: rb3 = s1
        (void)rb1; (void)rb2;
        h1 = rb3;                          // h0 = s0, h1 = s1
    }

    // ---- packs 1..4095; pack k stores pack k-1's quad after its 2nd step ----
    for (int k = 1; k < NPACK; ++k) {
        float4 ev = (k & 1) ? ebuf1 : ebuf0;
        int kp = k + 2; if (kp > NPACK-1) kp = NPACK-1;
        if (k & 1) ebuf1 = er4[kp]; else ebuf0 = er4[kp];

        float rbA, rbB, rbC, rbD;
        STEP(1, 0, ev.x, rbA)              // t=4k:   rbA = s_{4k-2}
        STEP(0, 1, ev.y, rbB)              // t=4k+1: rbB = s_{4k-1}
        if (l < NC) *(float4*)(scp + (k-1)*84 + n*4) = make_float4(h0, h1, rbA, rbB);
        STEP(1, 0, ev.z, rbC)              // t=4k+2: rbC = s_{4k}
        STEP(0, 1, ev.w, rbD)              // t=4k+3: rbD = s_{4k+1}
        h0 = rbC; h1 = rbD;
    }
    #undef STEP

    // ---- epilogue: buf0 = s_{16382}, buf1 = s_{16383} (never exchanged after their writes) ----
    float s2last = smem[l];                // s_{L-2}[n] for l<21
    float s3last = smem[64 + l];           // s_{L-1}[n] for l<21
    if (l < NC) {
        *(float4*)(scp + (NPACK-1)*84 + n*4) = make_float4(h0, h1, s2last, s3last);
        fin[n] = s3last;
    }
    __syncthreads();
    if (l == 0) {
        float bv = fin[0] + endt[0]; int bt = 0;
        #pragma unroll
        for (int j = 1; j < NC; ++j) {
            float v = fin[j] + endt[j];
            if (v > bv) { bv = v; bt = j; }
        }
        last_tag[b] = bt;
    }
}

// ---------------- K2b: parallel backpointer recovery ----------------
// bp[t][n] = first p with fl(fl(s_{t-1}[p]+T[p][n])+e[t][n]) == s_t[n]
__global__ __launch_bounds__(256) void k_bp(
    const float* __restrict__ emT, const float* __restrict__ sc,
    const float* __restrict__ trans, uint8_t* __restrict__ bp)
{
    int wave = threadIdx.x >> 6;
    int lane = threadIdx.x & 63;
    int ne   = lane < NC ? lane : NC-1;

    int bidx  = blockIdx.x;
    int b     = bidx >> 7;                              // 128 blocks per batch
    int tbase = (bidx & 127) * (4*T_PER) + wave*T_PER;

    const float* emb = emT + (size_t)b * NC * L;
    const float* scp = sc  + (size_t)b * NC * L;
    uint8_t*     bpb = bp  + (size_t)b * L * NC;

    float tc[NC];
    #pragma unroll
    for (int pp = 0; pp < NC; ++pp) tc[pp] = trans[pp*NC + ne];

    for (int t = tbase; t < tbase + T_PER; ++t) {
        if (t == 0) continue;
        float target = scp[(t>>2)*84 + ne*4 + (t&3)];
        float e      = emb[(size_t)ne * L + t];
        const float* sp = scp + ((t-1)>>2)*84 + ((t-1)&3);
        int fi = 0;
        #pragma unroll
        for (int pp = NC-1; pp >= 0; --pp) {
            float cand = (sp[pp*4] + tc[pp]) + e;
            if (cand == target) fi = pp;
        }
        if (lane < NC) bpb[(size_t)t * NC + ne] = (uint8_t)fi;
    }
}

// ---------------- K3a: per-chunk jump tables, SEGMENTED chase (exact) ----------------
__global__ __launch_bounds__(64) void k_jump(
    const uint8_t* __restrict__ bp, uint8_t* __restrict__ J)
{
    __shared__ uint32_t lds4[CHUNK*NC/4];    // 5376 B of bp rows [cs..ce)
    __shared__ uint8_t  segJ[8*NC];          // 168 B
    int l   = threadIdx.x;
    int bid = blockIdx.x;
    int b   = bid / (NCHUNKS-1);
    int k   = bid % (NCHUNKS-1) + 1;         // chunks 1..63
    int cs  = k * CHUNK;

    const uint32_t* src = (const uint32_t*)(bp + (size_t)b * L * NC + (size_t)cs * NC);
    for (int i = l; i < CHUNK*NC/4; i += 64) lds4[i] = src[i];
    __syncthreads();
    const uint8_t* lb = (const uint8_t*)lds4;

    // 168 = 8 segs x 21 hyps; chase c -> (s=c/21, h=c%21), rows s*32+31 .. s*32
    int c0 = l, c1 = l + 63, c2 = l + 126;
    bool v2 = (c2 < 8*NC);
    int t0 = c0 % NC, t1 = c1 % NC, t2 = v2 ? (c2 % NC) : 0;
    int r0 = (c0 / NC) * 32, r1 = (c1 / NC) * 32, r2 = v2 ? (c2 / NC) * 32 : 0;
    for (int i = 31; i >= 0; --i) {          // 3 independent chains -> pipelined
        t0 = lb[(r0+i)*NC + t0];
        t1 = lb[(r1+i)*NC + t1];
        if (v2) t2 = lb[(r2+i)*NC + t2];
    }
    segJ[c0] = (uint8_t)t0;
    segJ[c1] = (uint8_t)t1;
    if (v2) segJ[c2] = (uint8_t)t2;
    __syncthreads();

    if (l < NC) {
        int tag = l;
        #pragma unroll
        for (int s = 7; s >= 0; --s) tag = segJ[s*NC + tag];
        J[((size_t)b * NCHUNKS + k) * NC + l] = (uint8_t)tag;
    }
}

// ---------------- K3b: thread chunk entries through jump tables (LDS-staged J) ----------------
__global__ __launch_bounds__(64) void k_seq(
    const uint8_t* __restrict__ J, const int* __restrict__ last_tag,
    uint8_t* __restrict__ ent)
{
    __shared__ uint32_t ldsJ4[NB*NCHUNKS*NC/4];   // 21504 B
    int l = threadIdx.x;
    const uint32_t* src = (const uint32_t*)J;
    for (int i = l; i < NB*NCHUNKS*NC/4; i += 64) ldsJ4[i] = src[i];
    __syncthreads();
    const uint8_t* lj = (const uint8_t*)ldsJ4;

    if (l < NB) {
        int b = l;
        int tag = last_tag[b];                       // tag at t = L-1
        ent[b * NCHUNKS + 63] = (uint8_t)tag;
        for (int k = NCHUNKS-1; k >= 1; --k) {
            tag = lj[((size_t)b * NCHUNKS + k) * NC + tag];
            ent[b * NCHUNKS + (k-1)] = (uint8_t)tag;
        }
    }
}

// ---------------- K3c: per-chunk output, SEGMENTED re-walk from exact seed ----------------
__global__ __launch_bounds__(64) void k_out(
    const uint8_t* __restrict__ bp, const uint8_t* __restrict__ ent,
    int* __restrict__ out)
{
    __shared__ uint32_t lds4[CHUNK*NC/4];
    __shared__ uint8_t  segJ[8*NC];
    __shared__ uint8_t  E[8];
    __shared__ int      tags[CHUNK];
    int l   = threadIdx.x;
    int bid = blockIdx.x;
    int b   = bid >> 6;
    int k   = bid & (NCHUNKS-1);
    int cs  = k * CHUNK;

    const uint32_t* src = (const uint32_t*)(bp + (size_t)b * L * NC + (size_t)cs * NC);
    for (int i = l; i < CHUNK*NC/4; i += 64) lds4[i] = src[i];
    __syncthreads();
    const uint8_t* lb = (const uint8_t*)lds4;

    // phase 2: segment tables (chunk 0 seg 0 crosses t=0: its result is never used)
    int c0 = l, c1 = l + 63, c2 = l + 126;
    bool v2 = (c2 < 8*NC);
    int t0 = c0 % NC, t1 = c1 % NC, t2 = v2 ? (c2 % NC) : 0;
    int r0 = (c0 / NC) * 32, r1 = (c1 / NC) * 32, r2 = v2 ? (c2 / NC) * 32 : 0;
    for (int i = 31; i >= 0; --i) {
        t0 = lb[(r0+i)*NC + t0];
        t1 = lb[(r1+i)*NC + t1];
        if (v2) t2 = lb[(r2+i)*NC + t2];
    }
    segJ[c0] = (uint8_t)(t0 & 31);           // mask: chunk-0/seg-0 garbage stays in-bounds
    segJ[c1] = (uint8_t)(t1 & 31);
    if (v2) segJ[c2] = (uint8_t)(t2 & 31);
    __syncthreads();

    // phase 3: compose segment entry tags E[s] = tag at position cs + 32s + 31
    if (l == 0) {
        int tag = ent[b * NCHUNKS + k];              // exact tag at ce-1
        E[7] = (uint8_t)tag;
        #pragma unroll
        for (int s = 7; s >= 1; --s) { tag = segJ[s*NC + tag]; E[s-1] = (uint8_t)tag; }
    }
    __syncthreads();

    // phase 4: 8 lanes re-walk their 32 rows
    if (l < 8) {
        int tag = E[l];
        int rb  = l * 32;
        for (int i = 31; i >= 0; --i) {              // t = cs+rb+i down to cs+rb
            tags[rb + i] = tag;
            tag = lb[(rb+i)*NC + tag];               // hop at t=0 (chunk 0) unused
        }
    }
    __syncthreads();

    int4* ob = (int4*)(out + (size_t)b * L + cs);
    ob[l] = ((const int4*)tags)[l];                  // 64 lanes x int4 = 256 ints
}

extern "C" void kernel_launch(void* const* d_in, const int* in_sizes, int n_in,
                              void* d_out, int out_size, void* d_ws, size_t ws_size,
                              hipStream_t stream) {
    const float* x  = (const float*)d_in[0];
    const float* w1 = (const float*)d_in[1];
    const float* b1 = (const float*)d_in[2];
    const float* w2 = (const float*)d_in[3];
    const float* b2 = (const float*)d_in[4];
    const float* st = (const float*)d_in[5];
    const float* en = (const float*)d_in[6];
    const float* tr = (const float*)d_in[7];
    int* out = (int*)d_out;

    char* ws = (char*)d_ws;
    float*   em = (float*)ws;                                    // em_T: 22,020,096 B
    float*   sc = (float*)(ws + (size_t)NB*L*NC*4);              // packed scores: 22,020,096 B
    uint8_t* bp = (uint8_t*)(ws + (size_t)NB*L*NC*8);            // 5,505,024 B
    int*     lt = (int*)(ws + (size_t)NB*L*NC*9);                // int[NB]
    // J/ent alias the em region: em is dead after k_bp completes (stream-ordered).
    uint8_t* J   = (uint8_t*)ws;                                 // NB*64*21 = 21,504 B
    uint8_t* ent = (uint8_t*)ws + 21504;                         // NB*64 = 1,024 B

    k_conv  <<<dim3(NB*L/256),       dim3(256), 0, stream>>>(x, w1, b1, w2, b2, em);
    k_scores<<<dim3(NB),             dim3(64),  0, stream>>>(em, st, en, tr, sc, lt);
    k_bp    <<<dim3(NB*128),         dim3(256), 0, stream>>>(em, sc, tr, bp);
    k_jump  <<<dim3(NB*(NCHUNKS-1)), dim3(64),  0, stream>>>(bp, J);
    k_seq   <<<dim3(1),              dim3(64),  0, stream>>>(J, lt, ent);
    k_out   <<<dim3(NB*NCHUNKS),     dim3(64),  0, stream>>>(bp, ent, out);
}